// Round 5
// baseline (1025.638 us; speedup 1.0000x reference)
//
#include <hip/hip_runtime.h>
#include <hip/hip_bf16.h>
#include <stdint.h>

// GRU-style LanguageEncoder: T=64, B=256, VOCAB=32000, D=512, H=1024.
// Reference semantics: a = tanh(a_x + (r * h) @ w_h_a + b_a)  ((r*h) BEFORE matmul).
// Structure:
//   k_gather    : words_bf16[t*B+b][d] = bf16(embed[x]*(x>0))
//   k_transpose : w_i -> wit (3072x512) bf16 ; w_h -> wht (3072x1024) bf16
//   k_zero      : zero h buffer + barrier flags (+ rot slot 0)
//   k_gemm_gx   : gx = words @ w_i + b  (16384x3072, bf16), 128x128 MFMA tile
//   k_recur     : persistent 256-block kernel, 64 steps, 2 phases/step.
//   History (per-step): R2 RMW+fences 33us; R3 flags+fences 21.5; R6 atomic
//   reads 16.4 (atomic pipe op-rate-bound); R8 acquire-inv cached 12.8;
//   R9/R10 sc0sc1 bypass reads 12.4. R11 role-split FAILED (confounded).
//   R12 L2-local reads: fabric reads halved, dur UNCHANGED. R13 plain-store
//   exchange: WRITE_SIZE and dur IDENTICAL -> store class irrelevant.
//   R14 rotating slabs + cached first-touch reads: 12.4 -> 11.3 (only -0.5
//   us/phase) -> read path was never the floor either.
//   Remaining floor = the MONOLITHIC BARRIER PIPELINE: drain -> flag RMW ->
//   poll-detect ALL 64 producers (with an ATOMIC-load poll storm riding the
//   R6-proven op-rate-bound atomic pipe) -> only then 32 loads -> MFMA.
//   Detect + load-latency + compute are strictly additive.
//   R15: dataflow barrier. (1) polls use PLAIN sc0 sc1 loads (normal path,
//   line rate, off the atomic pipe). (2) chunked waits: k-chunk kb (256
//   h-cols) only needs producers jb' in [16kb,16kb+16); each wave polls
//   those 16 slots, issues that chunk's 8 cached loads, and MFMAs while
//   polling the next chunk (poll's vmcnt(0) completes the previous chunk's
//   loads). No intra-phase syncthreads; waves drift. Flag thresholds
//   identical to R14 (ph_Z=2t, ph_A=2t+1); arrive/store path unchanged.

#define TT 64
#define BB 256
#define DD 512
#define HH 1024
#define N3H 3072
#define SLAB (BB * HH)   // elements per h/rh snapshot (512 KB)

using frag  = __attribute__((ext_vector_type(8))) short;   // 8 bf16 (4 VGPRs)
using f32x4 = __attribute__((ext_vector_type(4))) float;   // MFMA accumulator

__device__ __forceinline__ uint16_t f2b(float f) {
    uint32_t u = __builtin_bit_cast(uint32_t, f);
    uint32_t r = u + 0x7FFFu + ((u >> 16) & 1u);   // round-to-nearest-even
    return (uint16_t)(r >> 16);
}
__device__ __forceinline__ float b2f(uint16_t b) {
    uint32_t u = ((uint32_t)b) << 16;
    return __builtin_bit_cast(float, u);
}

// Issue 8 x 16B L3-coherent loads (sc0 sc1: bypass L1/L2) from 64B-strided
// addresses. NO wait - caller uses counted vmcnt via WAIT8. (Fallback path.)
__device__ __forceinline__ void load8_issue(const uint16_t* p, frag* f) {
    asm volatile(
        "global_load_dwordx4 %0, %8, off sc0 sc1\n\t"
        "global_load_dwordx4 %1, %8, off offset:64 sc0 sc1\n\t"
        "global_load_dwordx4 %2, %8, off offset:128 sc0 sc1\n\t"
        "global_load_dwordx4 %3, %8, off offset:192 sc0 sc1\n\t"
        "global_load_dwordx4 %4, %8, off offset:256 sc0 sc1\n\t"
        "global_load_dwordx4 %5, %8, off offset:320 sc0 sc1\n\t"
        "global_load_dwordx4 %6, %8, off offset:384 sc0 sc1\n\t"
        "global_load_dwordx4 %7, %8, off offset:448 sc0 sc1"
        : "=&v"(f[0]), "=&v"(f[1]), "=&v"(f[2]), "=&v"(f[3]),
          "=&v"(f[4]), "=&v"(f[5]), "=&v"(f[6]), "=&v"(f[7])
        : "v"(p)
        : "memory");
}
// Normal cached-path issue (rotation slabs: first-touch guarantees freshness).
__device__ __forceinline__ void load8c(const uint16_t* p, frag* f) {
    asm volatile(
        "global_load_dwordx4 %0, %8, off\n\t"
        "global_load_dwordx4 %1, %8, off offset:64\n\t"
        "global_load_dwordx4 %2, %8, off offset:128\n\t"
        "global_load_dwordx4 %3, %8, off offset:192\n\t"
        "global_load_dwordx4 %4, %8, off offset:256\n\t"
        "global_load_dwordx4 %5, %8, off offset:320\n\t"
        "global_load_dwordx4 %6, %8, off offset:384\n\t"
        "global_load_dwordx4 %7, %8, off offset:448"
        : "=&v"(f[0]), "=&v"(f[1]), "=&v"(f[2]), "=&v"(f[3]),
          "=&v"(f[4]), "=&v"(f[5]), "=&v"(f[6]), "=&v"(f[7])
        : "v"(p)
        : "memory");
}

// counted wait: outstanding <= N. Ties the 8 frags so MFMA consumers depend
// on THIS asm's outputs (rule-18-safe without sched_barrier).
#define WAIT8(N, F)                                                       \
    asm volatile("s_waitcnt vmcnt(" #N ")"                                \
                 : "+v"((F)[0]), "+v"((F)[1]), "+v"((F)[2]),              \
                   "+v"((F)[3]), "+v"((F)[4]), "+v"((F)[5]),              \
                   "+v"((F)[6]), "+v"((F)[7]))

#define ZCON(KB, HF)                                                              \
    _Pragma("unroll")                                                             \
    for (int j = 0; j < 8; ++j) {                                                 \
        int kk = (KB) * 8 + j;                                                    \
        frag b0 = *(const frag*)(Wh + (l16)      * LDW + kk * 32 + quad * 8);     \
        frag b1 = *(const frag*)(Wh + (16 + l16) * LDW + kk * 32 + quad * 8);     \
        acc0 = __builtin_amdgcn_mfma_f32_16x16x32_bf16((HF)[j], b0, acc0, 0, 0, 0); \
        acc1 = __builtin_amdgcn_mfma_f32_16x16x32_bf16((HF)[j], b1, acc1, 0, 0, 0); \
    }

#define ACON(KB, RF)                                                              \
    _Pragma("unroll")                                                             \
    for (int j = 0; j < 8; ++j) {                                                 \
        int kk = (KB) * 8 + j;                                                    \
        frag b2 = *(const frag*)(Wh + (32 + l16) * LDW + kk * 32 + quad * 8);     \
        acc2 = __builtin_amdgcn_mfma_f32_16x16x32_bf16((RF)[j], b2, acc2, 0, 0, 0); \
    }

// ---------------- prep kernels ----------------

__global__ __launch_bounds__(256) void k_gather(const int* __restrict__ x,
                                                const float* __restrict__ embed,
                                                uint16_t* __restrict__ words) {
    int tid = blockIdx.x * 256 + threadIdx.x;
    int row = tid >> 6;
    int c8  = (tid & 63) << 3;
    int tok = x[row];
    float s = (tok > 0) ? 1.f : 0.f;
    const float4* src = (const float4*)(embed + (int64_t)tok * DD + c8);
    float4 v0 = src[0], v1 = src[1];
    float vals[8] = {v0.x, v0.y, v0.z, v0.w, v1.x, v1.y, v1.z, v1.w};
    union { uint16_t u[8]; uint4 q; } pk;
#pragma unroll
    for (int i = 0; i < 8; ++i) pk.u[i] = f2b(vals[i] * s);
    *(uint4*)(words + ((int64_t)row << 9) + c8) = pk.q;
}

// src (K x N) fp32 -> dst (N x K) bf16, 32x32 LDS tiles
__global__ void k_transpose(const float* __restrict__ src, uint16_t* __restrict__ dst,
                            int K, int N) {
    __shared__ float tile[32][33];
    int n0 = blockIdx.x * 32, k0 = blockIdx.y * 32;
    int tx = threadIdx.x, ty = threadIdx.y;   // (32, 8)
#pragma unroll
    for (int i = 0; i < 32; i += 8)
        tile[ty + i][tx] = src[(int64_t)(k0 + ty + i) * N + n0 + tx];
    __syncthreads();
#pragma unroll
    for (int i = 0; i < 32; i += 8)
        dst[(int64_t)(n0 + ty + i) * K + k0 + tx] = f2b(tile[tx][ty + i]);
}

__global__ void k_zero(uint4* p, int n16) {
    int i = blockIdx.x * blockDim.x + threadIdx.x;
    if (i < n16) p[i] = uint4{0u, 0u, 0u, 0u};
}

// ---------------- gx GEMM: 16384 x 3072 x 512 ----------------

__global__ __launch_bounds__(256) void k_gemm_gx(const uint16_t* __restrict__ A,
                                                 const uint16_t* __restrict__ BT,
                                                 const float* __restrict__ bias,
                                                 uint16_t* __restrict__ C) {
    __shared__ uint16_t As[128][72];
    __shared__ uint16_t Bs[128][72];
    int m0 = blockIdx.y * 128;
    int n0 = blockIdx.x * 128;
    int t = threadIdx.x;
    int wave = t >> 6, lane = t & 63, quad = lane >> 4, l16 = lane & 15;
    int wm = (wave & 1) * 64, wn = (wave >> 1) * 64;
    f32x4 acc[4][4] = {};

    int sr = t >> 1;
    int sc = (t & 1) * 32;

    for (int k0 = 0; k0 < DD; k0 += 64) {
        const uint4* ga = (const uint4*)(A + (int64_t)(m0 + sr) * DD + k0 + sc);
        uint4 a0 = ga[0], a1 = ga[1], a2 = ga[2], a3 = ga[3];
        const uint4* gb = (const uint4*)(BT + (int64_t)(n0 + sr) * DD + k0 + sc);
        uint4 b0 = gb[0], b1 = gb[1], b2 = gb[2], b3 = gb[3];
        __syncthreads();
        *(uint4*)&As[sr][sc]      = a0;
        *(uint4*)&As[sr][sc + 8]  = a1;
        *(uint4*)&As[sr][sc + 16] = a2;
        *(uint4*)&As[sr][sc + 24] = a3;
        *(uint4*)&Bs[sr][sc]      = b0;
        *(uint4*)&Bs[sr][sc + 8]  = b1;
        *(uint4*)&Bs[sr][sc + 16] = b2;
        *(uint4*)&Bs[sr][sc + 24] = b3;
        __syncthreads();
#pragma unroll
        for (int kk = 0; kk < 64; kk += 32) {
            frag af[4], bf[4];
#pragma unroll
            for (int mi = 0; mi < 4; ++mi)
                af[mi] = *(const frag*)&As[wm + mi * 16 + l16][kk + quad * 8];
#pragma unroll
            for (int ni = 0; ni < 4; ++ni)
                bf[ni] = *(const frag*)&Bs[wn + ni * 16 + l16][kk + quad * 8];
#pragma unroll
            for (int mi = 0; mi < 4; ++mi)
#pragma unroll
                for (int ni = 0; ni < 4; ++ni)
                    acc[mi][ni] = __builtin_amdgcn_mfma_f32_16x16x32_bf16(
                        af[mi], bf[ni], acc[mi][ni], 0, 0, 0);
        }
    }
#pragma unroll
    for (int ni = 0; ni < 4; ++ni) {
        int col = n0 + wn + ni * 16 + l16;
        float bv = bias[col];
#pragma unroll
        for (int mi = 0; mi < 4; ++mi)
#pragma unroll
            for (int r = 0; r < 4; ++r) {
                int row = m0 + wm + mi * 16 + quad * 4 + r;
                C[(int64_t)row * N3H + col] = f2b(acc[mi][ni][r] + bv);
            }
    }
}

// ---------------- recurrence (R15) ----------------
// grid (mg=4, jb=64): linear id = mg + 4*jb -> each m-group's 64 blocks sit on
// XCDs {mg, mg+4}. LDS: Wh[48][1032] bf16 (99KB).
// ROT=1: rotating slabs (R14) + chunked dataflow waits (R15). h slot s = state
// before step s; rh slot t written in Z(t), read in A(t). Flag counters
// monotonic: after top-arrive of step t flag=2t, after Z-arrive flag=2t+1.
// Z(t) chunk kb waits producers' flag>=2t; A(t) waits >=2t+1.
// ROT=0: exact R13 static-buffer behavior (sc0sc1 bypass reads, monolithic).

template <bool ROT>
__global__ __launch_bounds__(256, 1) void k_recur(const uint16_t* __restrict__ gx,
                                                  const uint16_t* __restrict__ wht,
                                                  uint16_t* __restrict__ hb,
                                                  uint16_t* __restrict__ rb,
                                                  unsigned int* __restrict__ bar,
                                                  float* __restrict__ out) {
    extern __shared__ uint16_t Wh[];           // 48 rows x 1032 (1024 + 8 pad)
    const int LDW = HH + 8;
    int mg = blockIdx.x;        // 0..3  (fast dim -> XCD pairing)
    int jb = blockIdx.y;        // 0..63
    int j0 = jb * 16;
    int m0 = mg * 64;
    int t = threadIdx.x, wave = t >> 6, lane = t & 63, quad = lane >> 4, l16 = lane & 15;

    // load w_h slice: gathered rows s*16+i  <-  wht row s*HH + j0 + i
    for (int c = t; c < 48 * 128; c += 256) {
        int row = c >> 7;
        int off = (c & 127) << 3;
        int s = row >> 4, i = row & 15;
        *(uint4*)(Wh + row * LDW + off) =
            *(const uint4*)(wht + (int64_t)(s * HH + j0 + i) * HH + off);
    }
    __syncthreads();

    float hp[4]   = {0.f, 0.f, 0.f, 0.f};
    float zg[4];
    float osum[4] = {0.f, 0.f, 0.f, 0.f};
    int brow = m0 + wave * 16 + quad * 4;
    int jcol = j0 + l16;
    const int jc4 = j0 + (l16 & ~3);         // 4-col pack base
    unsigned int* flags = bar + mg * 1024;   // 64 slots x 64B stride
    unsigned int phase = 0;                  // fallback path only

    // this lane's MFMA A-row offset within a slab
    const int64_t arow = (int64_t)(m0 + wave * 16 + l16) * HH + quad * 8;

    auto bar_arrive = [&]() {
        __syncthreads();   // compiler emits vmcnt(0) drain before s_barrier
        if (t == 0)
            (void)__hip_atomic_fetch_add(&flags[jb * 16], 1u, __ATOMIC_RELAXED,
                                         __HIP_MEMORY_SCOPE_AGENT);
    };
    // monolithic wait (fallback path only): wave0 polls all 64 slots
    auto bar_wait = [&](unsigned int ph) {
        if (wave == 0) {
            long guard = 0;
            for (;;) {
                unsigned int v = __hip_atomic_load(&flags[lane * 16], __ATOMIC_RELAXED,
                                                   __HIP_MEMORY_SCOPE_AGENT);
                if (__all((int)(v >= ph))) break;
                __builtin_amdgcn_s_sleep(1);
                if (++guard > (1L << 13)) break;   // fail fast (absmax), never wedge
            }
        }
        __syncthreads();
    };
    // chunked wait (ROT path): EVERY wave polls the 16 producer slots of
    // k-chunk c with PLAIN sc0sc1 loads (normal path, off the atomic pipe).
    // Each iteration ends vmcnt(0) -> also completes previously-issued slab
    // loads, pipelining detect/load/MFMA. No intra-phase syncthreads.
    auto wait_chunk = [&](unsigned int ph, int c) {
        const unsigned int* slot = flags + (c * 16 + l16) * 16;
        long guard = 0;
        for (;;) {
            unsigned int v;
            asm volatile("global_load_dword %0, %1, off sc0 sc1\n\t"
                         "s_waitcnt vmcnt(0)"
                         : "=v"(v) : "v"(slot) : "memory");
            if (__all((int)(v >= ph))) break;
            __builtin_amdgcn_s_sleep(1);
            if (++guard > (1L << 13)) break;   // fail fast (absmax), never wedge
        }
    };

    // pack lanes l16^1, l16^2 -> one uint64 (4 adjacent cols), written by the
    // (l16%4==0) lane as a plain sc0sc1 store (write-through to L3; required
    // for cross-XCD visibility). vmcnt-drained before the flag RMW.
    auto store4 = [&](uint16_t* base, int r, uint32_t mine) {
        uint32_t p2 = mine | (((uint32_t)__shfl_xor((int)mine, 1)) << 16);
        uint32_t hi = (uint32_t)__shfl_xor((int)p2, 2);
        if ((l16 & 3) == 0) {
            uint64_t p4 = (uint64_t)p2 | ((uint64_t)hi << 32);
            uint64_t* dst = (uint64_t*)base + (int64_t)(brow + r) * (HH / 4) + (jc4 >> 2);
            asm volatile("global_store_dwordx2 %0, %1, off sc0 sc1"
                         :: "v"(dst), "v"(p4) : "memory");
        }
    };

    for (int step = 0; step < TT; ++step) {
        const uint16_t* hsrc;  uint16_t* rhdst;
        const uint16_t* rhsrc; uint16_t* hdst;
        if constexpr (ROT) {
            hsrc  = hb + (size_t)step * SLAB;        // state before this step
            hdst  = hb + (size_t)(step + 1) * SLAB;
            rhsrc = rb + (size_t)step * SLAB;
            rhdst = rb + (size_t)step * SLAB;
        } else {
            hsrc = hb; hdst = hb; rhsrc = rb; rhdst = rb;
        }

        // ---- arrive: h(step) stores drained + flag (producers of h) ----
        if (step > 0) bar_arrive();

        // prefetch this step's gx scalars (immutable, cached) - issued before
        // the waits so their latency hides under the polls
        uint16_t gzv[4], grv[4], gav[4];
        {
            const uint16_t* gxrow = gx + (int64_t)step * BB * N3H;
#pragma unroll
            for (int r = 0; r < 4; ++r) {
                const uint16_t* g = gxrow + (int64_t)(brow + r) * N3H + jcol;
                gzv[r] = g[0]; grv[r] = g[HH]; gav[r] = g[2 * HH];
            }
        }

        // ---- phase Z: h @ w_h_zr (acc0 = z-col, acc1 = r-col) ----
        {
            f32x4 acc0 = {}, acc1 = {};
            if constexpr (ROT) {
                const unsigned int phZ = 2u * (unsigned)step;   // 0 at step 0: passes
                const uint16_t* hrow = hsrc + arow;
                frag h0[8], h1[8], h2[8], h3[8];
                wait_chunk(phZ, 0); load8c(hrow,       h0);
                wait_chunk(phZ, 1); load8c(hrow + 256, h1);
                WAIT8(8, h0); ZCON(0, h0);
                wait_chunk(phZ, 2); load8c(hrow + 512, h2);
                WAIT8(8, h1); ZCON(1, h1);
                wait_chunk(phZ, 3); load8c(hrow + 768, h3);
                WAIT8(8, h2); ZCON(2, h2);
                WAIT8(0, h3); ZCON(3, h3);
            } else {
                if (step > 0) bar_wait(++phase);
                asm volatile("s_waitcnt vmcnt(0)" ::: "memory");
                const uint16_t* hrow = hsrc + arow;
                frag h0[8], h1[8], h2[8], h3[8];
                load8_issue(hrow,       h0);
                load8_issue(hrow + 256, h1);
                load8_issue(hrow + 512, h2);
                load8_issue(hrow + 768, h3);
                WAIT8(24, h0); ZCON(0, h0);
                WAIT8(16, h1); ZCON(1, h1);
                WAIT8(8,  h2); ZCON(2, h2);
                WAIT8(0,  h3); ZCON(3, h3);
            }
#pragma unroll
            for (int r = 0; r < 4; ++r) {
                float zp = b2f(gzv[r]) + acc0[r];        // bias folded into gx
                float rp = b2f(grv[r]) + acc1[r];
                float z  = 1.f / (1.f + __expf(-zp));
                float rg = 1.f / (1.f + __expf(-rp));
                zg[r] = z;
                store4(rhdst, r, (uint32_t)f2b(rg * hp[r]));
            }
        }

        // ---- arrive: rh stores drained + flag (producers of rh) ----
        bar_arrive();

        // ---- phase A: rh @ w_h_a (acc2), gate + h update ----
        {
            f32x4 acc2 = {};
            if constexpr (ROT) {
                const unsigned int phA = 2u * (unsigned)step + 1u;
                const uint16_t* rrow = rhsrc + arow;
                frag r0[8], r1[8], r2[8], r3[8];
                wait_chunk(phA, 0); load8c(rrow,       r0);
                wait_chunk(phA, 1); load8c(rrow + 256, r1);
                WAIT8(8, r0); ACON(0, r0);
                wait_chunk(phA, 2); load8c(rrow + 512, r2);
                WAIT8(8, r1); ACON(1, r1);
                wait_chunk(phA, 3); load8c(rrow + 768, r3);
                WAIT8(8, r2); ACON(2, r2);
                WAIT8(0, r3); ACON(3, r3);
            } else {
                bar_wait(++phase);
                asm volatile("s_waitcnt vmcnt(0)" ::: "memory");
                const uint16_t* rrow = rhsrc + arow;
                frag r0[8], r1[8], r2[8], r3[8];
                load8_issue(rrow,       r0);
                load8_issue(rrow + 256, r1);
                load8_issue(rrow + 512, r2);
                load8_issue(rrow + 768, r3);
                WAIT8(24, r0); ACON(0, r0);
                WAIT8(16, r1); ACON(1, r1);
                WAIT8(8,  r2); ACON(2, r2);
                WAIT8(0,  r3); ACON(3, r3);
            }
#pragma unroll
            for (int r = 0; r < 4; ++r) {
                float a  = tanhf(b2f(gav[r]) + acc2[r]);
                float hn = (1.f - zg[r]) * hp[r] + zg[r] * a;
                osum[r] += hn;
                hp[r] = hn;
                store4(hdst, r, (uint32_t)f2b(hn));
            }
        }
    }
#pragma unroll
    for (int r = 0; r < 4; ++r)
        out[(int64_t)(brow + r) * HH + jcol] = osum[r];
}

// ---------------- launch ----------------

extern "C" void kernel_launch(void* const* d_in, const int* in_sizes, int n_in,
                              void* d_out, int out_size, void* d_ws, size_t ws_size,
                              hipStream_t stream) {
    const int*   x     = (const int*)d_in[0];
    const float* embed = (const float*)d_in[1];
    const float* w_i   = (const float*)d_in[2];
    const float* w_h   = (const float*)d_in[3];
    const float* bias  = (const float*)d_in[4];
    float* out = (float*)d_out;

    char* ws = (char*)d_ws;
    uint16_t* gx    = (uint16_t*)(ws);                 // 16384*3072*2 = 100663296
    uint16_t* wit   = (uint16_t*)(ws + 100663296);     // 3072*512*2  =   3145728
    uint16_t* wht   = (uint16_t*)(ws + 103809024);     // 3072*1024*2 =   6291456
    uint16_t* words = (uint16_t*)(ws + 110100480);     // 16384*512*2 =  16777216
    uint16_t* hbuf  = (uint16_t*)(ws + 126877696);     // 256*1024*2  =    524288
    uint16_t* rhbuf = (uint16_t*)(ws + 127401984);     // 256*1024*2  =    524288
    unsigned int* flags = (unsigned int*)(ws + 127926272); // 4*1024*4 = 16384
    // rotation region (R14): 65 h slots + 64 rh slots of 512KB
    const size_t ROT_BASE = 127942656;                 // 16KB-aligned
    uint16_t* hrot  = (uint16_t*)(ws + ROT_BASE);                    // 65*524288
    uint16_t* rhrot = (uint16_t*)(ws + ROT_BASE + 65ull * 524288);   // 64*524288
    const size_t ROT_NEED = ROT_BASE + (65ull + 64ull) * 524288;     // 195575808
    const bool rot = ws_size >= ROT_NEED;

    k_gather<<<4096, 256, 0, stream>>>(x, embed, words);
    k_transpose<<<dim3(96, 16), dim3(32, 8), 0, stream>>>(w_i, wit, DD, N3H);
    k_transpose<<<dim3(96, 32), dim3(32, 8), 0, stream>>>(w_h, wht, HH, N3H);
    // zero static hbuf + rhbuf + flags (contiguous 1048576 + 16384 bytes)
    k_zero<<<261, 256, 0, stream>>>((uint4*)(ws + 126877696), (1048576 + 16384) / 16);
    if (rot)   // zero h rotation slot 0 (state before step 0)
        k_zero<<<128, 256, 0, stream>>>((uint4*)hrot, 524288 / 16);
    k_gemm_gx<<<dim3(24, 128), 256, 0, stream>>>(words, wit, bias, gx);
    if (rot)
        k_recur<true><<<dim3(4, 64), 256, 48 * (HH + 8) * 2, stream>>>(
            gx, wht, hrot, rhrot, flags, out);
    else
        k_recur<false><<<dim3(4, 64), 256, 48 * (HH + 8) * 2, stream>>>(
            gx, wht, hbuf, rhbuf, flags, out);
}

// Round 6
// 894.923 us; speedup vs baseline: 1.1461x; 1.1461x over previous
//
#include <hip/hip_runtime.h>
#include <hip/hip_bf16.h>
#include <stdint.h>

// GRU-style LanguageEncoder: T=64, B=256, VOCAB=32000, D=512, H=1024.
// Reference semantics: a = tanh(a_x + (r * h) @ w_h_a + b_a)  ((r*h) BEFORE matmul).
// Structure:
//   k_gather    : words_bf16[t*B+b][d] = bf16(embed[x]*(x>0))
//   k_transpose : w_i -> wit (3072x512) bf16 ; w_h -> wht (3072x1024) bf16
//   k_zero      : zero h buffer + barrier flags (+ rot slot 0 + flags2)
//   k_gemm_gx   : gx = words @ w_i + b  (16384x3072, bf16), 128x128 MFMA tile
//   k_recur     : persistent 256-block kernel, 64 steps, 2 phases/step.
//   History (per-step): R2 RMW+fences 33us; R3 flags+fences 21.5; R6 atomic
//   reads 16.4 (atomic pipe op-rate-bound); R8 acquire-inv cached 12.8;
//   R9/R10 sc0sc1 bypass reads 12.4. R11 role-split FAILED (confounded).
//   R12 L2-local reads: fabric reads halved, dur UNCHANGED -> reads off
//   critical path. R13 plain-store exchange: identical -> store class
//   irrelevant. R14 rotating slabs + cached first-touch reads: 11.3 (best).
//   R15 chunked per-wave polls: 13.2 REGRESSION -> poll multiplication hurts;
//   polls perturb the thing they wait on.
//   Surviving theory: FLAG-TRAFFIC CONTENTION at the coherence point. 256
//   producer RMWs land on 4x4KB flag regions while 256 wave0s x 64 lanes
//   hammer the same lines with s_sleep(1)-paced ATOMIC polls; the last
//   arrive and the detecting load queue behind the storm. Invariant to all
//   data-path changes - matches the ledger.
//   R16 = R14 data path byte-identical + de-contended barrier:
//   (1) arrive: plain sc0sc1 STORE of monotonic epoch (single writer/slot),
//       no RMW; ordering via the existing pre-store __syncthreads vmcnt drain.
//   (2) flag slots restrided 64B->256B, groups 4KB->16KB apart (spread lines
//       and L3 slices; producer stores don't fight polls on the same line).
//   (3) poll: wave0-only plain sc0sc1 loads, s_sleep(4) pacing (lower rate,
//       off the atomic pipe).
//   Epochs: top-arrive of step t stores 2t (h(t) complete); Z-arrive stores
//   2t+1 (rh(t) complete). Z(t>0) waits >=2t; A(t) waits >=2t+1.

#define TT 64
#define BB 256
#define DD 512
#define HH 1024
#define N3H 3072
#define SLAB (BB * HH)   // elements per h/rh snapshot (512 KB)

using frag  = __attribute__((ext_vector_type(8))) short;   // 8 bf16 (4 VGPRs)
using f32x4 = __attribute__((ext_vector_type(4))) float;   // MFMA accumulator

__device__ __forceinline__ uint16_t f2b(float f) {
    uint32_t u = __builtin_bit_cast(uint32_t, f);
    uint32_t r = u + 0x7FFFu + ((u >> 16) & 1u);   // round-to-nearest-even
    return (uint16_t)(r >> 16);
}
__device__ __forceinline__ float b2f(uint16_t b) {
    uint32_t u = ((uint32_t)b) << 16;
    return __builtin_bit_cast(float, u);
}

// Issue 8 x 16B L3-coherent loads (sc0 sc1: bypass L1/L2) from 64B-strided
// addresses. NO wait - caller uses counted vmcnt via WAIT8. (Fallback path.)
__device__ __forceinline__ void load8_issue(const uint16_t* p, frag* f) {
    asm volatile(
        "global_load_dwordx4 %0, %8, off sc0 sc1\n\t"
        "global_load_dwordx4 %1, %8, off offset:64 sc0 sc1\n\t"
        "global_load_dwordx4 %2, %8, off offset:128 sc0 sc1\n\t"
        "global_load_dwordx4 %3, %8, off offset:192 sc0 sc1\n\t"
        "global_load_dwordx4 %4, %8, off offset:256 sc0 sc1\n\t"
        "global_load_dwordx4 %5, %8, off offset:320 sc0 sc1\n\t"
        "global_load_dwordx4 %6, %8, off offset:384 sc0 sc1\n\t"
        "global_load_dwordx4 %7, %8, off offset:448 sc0 sc1"
        : "=&v"(f[0]), "=&v"(f[1]), "=&v"(f[2]), "=&v"(f[3]),
          "=&v"(f[4]), "=&v"(f[5]), "=&v"(f[6]), "=&v"(f[7])
        : "v"(p)
        : "memory");
}

// counted wait: outstanding <= N. Ties the 8 frags so MFMA consumers depend
// on THIS asm's outputs (rule-18-safe without sched_barrier).
#define WAIT8(N, F)                                                       \
    asm volatile("s_waitcnt vmcnt(" #N ")"                                \
                 : "+v"((F)[0]), "+v"((F)[1]), "+v"((F)[2]),              \
                   "+v"((F)[3]), "+v"((F)[4]), "+v"((F)[5]),              \
                   "+v"((F)[6]), "+v"((F)[7]))

#define ZCON(KB, HF)                                                              \
    _Pragma("unroll")                                                             \
    for (int j = 0; j < 8; ++j) {                                                 \
        int kk = (KB) * 8 + j;                                                    \
        frag b0 = *(const frag*)(Wh + (l16)      * LDW + kk * 32 + quad * 8);     \
        frag b1 = *(const frag*)(Wh + (16 + l16) * LDW + kk * 32 + quad * 8);     \
        acc0 = __builtin_amdgcn_mfma_f32_16x16x32_bf16((HF)[j], b0, acc0, 0, 0, 0); \
        acc1 = __builtin_amdgcn_mfma_f32_16x16x32_bf16((HF)[j], b1, acc1, 0, 0, 0); \
    }

#define ACON(KB, RF)                                                              \
    _Pragma("unroll")                                                             \
    for (int j = 0; j < 8; ++j) {                                                 \
        int kk = (KB) * 8 + j;                                                    \
        frag b2 = *(const frag*)(Wh + (32 + l16) * LDW + kk * 32 + quad * 8);     \
        acc2 = __builtin_amdgcn_mfma_f32_16x16x32_bf16((RF)[j], b2, acc2, 0, 0, 0); \
    }

// ---------------- prep kernels ----------------

__global__ __launch_bounds__(256) void k_gather(const int* __restrict__ x,
                                                const float* __restrict__ embed,
                                                uint16_t* __restrict__ words) {
    int tid = blockIdx.x * 256 + threadIdx.x;
    int row = tid >> 6;
    int c8  = (tid & 63) << 3;
    int tok = x[row];
    float s = (tok > 0) ? 1.f : 0.f;
    const float4* src = (const float4*)(embed + (int64_t)tok * DD + c8);
    float4 v0 = src[0], v1 = src[1];
    float vals[8] = {v0.x, v0.y, v0.z, v0.w, v1.x, v1.y, v1.z, v1.w};
    union { uint16_t u[8]; uint4 q; } pk;
#pragma unroll
    for (int i = 0; i < 8; ++i) pk.u[i] = f2b(vals[i] * s);
    *(uint4*)(words + ((int64_t)row << 9) + c8) = pk.q;
}

// src (K x N) fp32 -> dst (N x K) bf16, 32x32 LDS tiles
__global__ void k_transpose(const float* __restrict__ src, uint16_t* __restrict__ dst,
                            int K, int N) {
    __shared__ float tile[32][33];
    int n0 = blockIdx.x * 32, k0 = blockIdx.y * 32;
    int tx = threadIdx.x, ty = threadIdx.y;   // (32, 8)
#pragma unroll
    for (int i = 0; i < 32; i += 8)
        tile[ty + i][tx] = src[(int64_t)(k0 + ty + i) * N + n0 + tx];
    __syncthreads();
#pragma unroll
    for (int i = 0; i < 32; i += 8)
        dst[(int64_t)(n0 + ty + i) * K + k0 + tx] = f2b(tile[tx][ty + i]);
}

__global__ void k_zero(uint4* p, int n16) {
    int i = blockIdx.x * blockDim.x + threadIdx.x;
    if (i < n16) p[i] = uint4{0u, 0u, 0u, 0u};
}

// ---------------- gx GEMM: 16384 x 3072 x 512 ----------------

__global__ __launch_bounds__(256) void k_gemm_gx(const uint16_t* __restrict__ A,
                                                 const uint16_t* __restrict__ BT,
                                                 const float* __restrict__ bias,
                                                 uint16_t* __restrict__ C) {
    __shared__ uint16_t As[128][72];
    __shared__ uint16_t Bs[128][72];
    int m0 = blockIdx.y * 128;
    int n0 = blockIdx.x * 128;
    int t = threadIdx.x;
    int wave = t >> 6, lane = t & 63, quad = lane >> 4, l16 = lane & 15;
    int wm = (wave & 1) * 64, wn = (wave >> 1) * 64;
    f32x4 acc[4][4] = {};

    int sr = t >> 1;
    int sc = (t & 1) * 32;

    for (int k0 = 0; k0 < DD; k0 += 64) {
        const uint4* ga = (const uint4*)(A + (int64_t)(m0 + sr) * DD + k0 + sc);
        uint4 a0 = ga[0], a1 = ga[1], a2 = ga[2], a3 = ga[3];
        const uint4* gb = (const uint4*)(BT + (int64_t)(n0 + sr) * DD + k0 + sc);
        uint4 b0 = gb[0], b1 = gb[1], b2 = gb[2], b3 = gb[3];
        __syncthreads();
        *(uint4*)&As[sr][sc]      = a0;
        *(uint4*)&As[sr][sc + 8]  = a1;
        *(uint4*)&As[sr][sc + 16] = a2;
        *(uint4*)&As[sr][sc + 24] = a3;
        *(uint4*)&Bs[sr][sc]      = b0;
        *(uint4*)&Bs[sr][sc + 8]  = b1;
        *(uint4*)&Bs[sr][sc + 16] = b2;
        *(uint4*)&Bs[sr][sc + 24] = b3;
        __syncthreads();
#pragma unroll
        for (int kk = 0; kk < 64; kk += 32) {
            frag af[4], bf[4];
#pragma unroll
            for (int mi = 0; mi < 4; ++mi)
                af[mi] = *(const frag*)&As[wm + mi * 16 + l16][kk + quad * 8];
#pragma unroll
            for (int ni = 0; ni < 4; ++ni)
                bf[ni] = *(const frag*)&Bs[wn + ni * 16 + l16][kk + quad * 8];
#pragma unroll
            for (int mi = 0; mi < 4; ++mi)
#pragma unroll
                for (int ni = 0; ni < 4; ++ni)
                    acc[mi][ni] = __builtin_amdgcn_mfma_f32_16x16x32_bf16(
                        af[mi], bf[ni], acc[mi][ni], 0, 0, 0);
        }
    }
#pragma unroll
    for (int ni = 0; ni < 4; ++ni) {
        int col = n0 + wn + ni * 16 + l16;
        float bv = bias[col];
#pragma unroll
        for (int mi = 0; mi < 4; ++mi)
#pragma unroll
            for (int r = 0; r < 4; ++r) {
                int row = m0 + wm + mi * 16 + quad * 4 + r;
                C[(int64_t)row * N3H + col] = f2b(acc[mi][ni][r] + bv);
            }
    }
}

// ---------------- recurrence (R16) ----------------
// grid (mg=4, jb=64): linear id = mg + 4*jb -> each m-group's 64 blocks sit on
// XCDs {mg, mg+4}. LDS: Wh[48][1032] bf16 (99KB).
// ROT=1: R14 data path (rotating slabs, cached first-touch reads, sc0sc1
// exchange stores) + de-contended epoch barrier (plain-store arrive, strided
// slots, wave0 sc0sc1 poll with s_sleep(4)).
// ROT=0: exact R13 static-buffer behavior (sc0sc1 bypass reads, RMW flags).

template <bool ROT>
__global__ __launch_bounds__(256, 1) void k_recur(const uint16_t* __restrict__ gx,
                                                  const uint16_t* __restrict__ wht,
                                                  uint16_t* __restrict__ hb,
                                                  uint16_t* __restrict__ rb,
                                                  unsigned int* __restrict__ bar,
                                                  unsigned int* __restrict__ bar2,
                                                  float* __restrict__ out) {
    extern __shared__ uint16_t Wh[];           // 48 rows x 1032 (1024 + 8 pad)
    const int LDW = HH + 8;
    int mg = blockIdx.x;        // 0..3  (fast dim -> XCD pairing)
    int jb = blockIdx.y;        // 0..63
    int j0 = jb * 16;
    int m0 = mg * 64;
    int t = threadIdx.x, wave = t >> 6, lane = t & 63, quad = lane >> 4, l16 = lane & 15;

    // load w_h slice: gathered rows s*16+i  <-  wht row s*HH + j0 + i
    for (int c = t; c < 48 * 128; c += 256) {
        int row = c >> 7;
        int off = (c & 127) << 3;
        int s = row >> 4, i = row & 15;
        *(uint4*)(Wh + row * LDW + off) =
            *(const uint4*)(wht + (int64_t)(s * HH + j0 + i) * HH + off);
    }
    __syncthreads();

    float hp[4]   = {0.f, 0.f, 0.f, 0.f};
    float zg[4];
    float osum[4] = {0.f, 0.f, 0.f, 0.f};
    int brow = m0 + wave * 16 + quad * 4;
    int jcol = j0 + l16;
    const int jc4 = j0 + (l16 & ~3);         // 4-col pack base
    unsigned int* flags  = bar  + mg * 1024;   // fallback: 64 slots x 64B stride
    unsigned int* flags2 = bar2 + mg * 4096;   // ROT: 64 slots x 256B stride
    unsigned int phase = 0;                    // fallback path only

    // this lane's MFMA A-row offset within a slab
    const int64_t arow = (int64_t)(m0 + wave * 16 + l16) * HH + quad * 8;

    // ROT arrive: drain data stores (syncthreads -> per-wave vmcnt(0) before
    // s_barrier), then t==0 plain sc0sc1 store of the epoch (single writer,
    // monotonic). No atomic pipe, no RMW.
    auto arrive_epoch = [&](unsigned int ep) {
        __syncthreads();
        if (t == 0) {
            unsigned int* slot = flags2 + jb * 64;
            asm volatile("global_store_dword %0, %1, off sc0 sc1"
                         :: "v"(slot), "v"(ep) : "memory");
        }
    };
    // ROT wait: wave0 polls 64 strided slots with plain sc0sc1 loads,
    // s_sleep(4) pacing; then block-wide syncthreads.
    auto wait_epoch = [&](unsigned int ep) {
        if (wave == 0) {
            const unsigned int* slot = flags2 + lane * 64;
            long guard = 0;
            for (;;) {
                unsigned int v;
                asm volatile("global_load_dword %0, %1, off sc0 sc1\n\t"
                             "s_waitcnt vmcnt(0)"
                             : "=v"(v) : "v"(slot) : "memory");
                if (__all((int)(v >= ep))) break;
                __builtin_amdgcn_s_sleep(4);
                if (++guard > (1L << 13)) break;   // fail fast (absmax), never wedge
            }
        }
        __syncthreads();
    };

    // fallback barrier (R13): RMW flags + atomic poll
    auto bar_arrive = [&]() {
        __syncthreads();
        if (t == 0)
            (void)__hip_atomic_fetch_add(&flags[jb * 16], 1u, __ATOMIC_RELAXED,
                                         __HIP_MEMORY_SCOPE_AGENT);
    };
    auto bar_wait = [&](unsigned int ph) {
        if (wave == 0) {
            long guard = 0;
            for (;;) {
                unsigned int v = __hip_atomic_load(&flags[lane * 16], __ATOMIC_RELAXED,
                                                   __HIP_MEMORY_SCOPE_AGENT);
                if (__all((int)(v >= ph))) break;
                __builtin_amdgcn_s_sleep(1);
                if (++guard > (1L << 13)) break;
            }
        }
        __syncthreads();
    };

    // pack lanes l16^1, l16^2 -> one uint64 (4 adjacent cols), written by the
    // (l16%4==0) lane as a plain sc0sc1 store (write-through to the coherence
    // point; required for cross-XCD visibility). vmcnt-drained before flag.
    auto store4 = [&](uint16_t* base, int r, uint32_t mine) {
        uint32_t p2 = mine | (((uint32_t)__shfl_xor((int)mine, 1)) << 16);
        uint32_t hi = (uint32_t)__shfl_xor((int)p2, 2);
        if ((l16 & 3) == 0) {
            uint64_t p4 = (uint64_t)p2 | ((uint64_t)hi << 32);
            uint64_t* dst = (uint64_t*)base + (int64_t)(brow + r) * (HH / 4) + (jc4 >> 2);
            asm volatile("global_store_dwordx2 %0, %1, off sc0 sc1"
                         :: "v"(dst), "v"(p4) : "memory");
        }
    };

    for (int step = 0; step < TT; ++step) {
        const uint16_t* hsrc;  uint16_t* rhdst;
        const uint16_t* rhsrc; uint16_t* hdst;
        if constexpr (ROT) {
            hsrc  = hb + (size_t)step * SLAB;        // state before this step
            hdst  = hb + (size_t)(step + 1) * SLAB;
            rhsrc = rb + (size_t)step * SLAB;
            rhdst = rb + (size_t)step * SLAB;
        } else {
            hsrc = hb; hdst = hb; rhsrc = rb; rhdst = rb;
        }

        // ---- arrive: h(step) fully written by this block (epoch 2t) ----
        if (step > 0) {
            if constexpr (ROT) arrive_epoch(2u * (unsigned)step);
            else               bar_arrive();
        }

        // prefetch this step's gx scalars (immutable, cached) - issued between
        // arrive and wait to hide under the poll
        uint16_t gzv[4], grv[4], gav[4];
        {
            const uint16_t* gxrow = gx + (int64_t)step * BB * N3H;
#pragma unroll
            for (int r = 0; r < 4; ++r) {
                const uint16_t* g = gxrow + (int64_t)(brow + r) * N3H + jcol;
                gzv[r] = g[0]; grv[r] = g[HH]; gav[r] = g[2 * HH];
            }
        }

        if (step > 0) {
            if constexpr (ROT) wait_epoch(2u * (unsigned)step);
            else               bar_wait(++phase);
        }

        // ---- phase Z: h @ w_h_zr (acc0 = z-col, acc1 = r-col) ----
        {
            f32x4 acc0 = {}, acc1 = {};
            if constexpr (ROT) {
                const uint16_t* hrow = hsrc + arow;
#pragma unroll
                for (int kb = 0; kb < 4; ++kb) {
                    frag hf[8];
#pragma unroll
                    for (int j = 0; j < 8; ++j)
                        hf[j] = *(const frag*)(hrow + kb * 256 + j * 32);
                    ZCON(kb, hf);
                }
            } else {
                asm volatile("s_waitcnt vmcnt(0)" ::: "memory");
                const uint16_t* hrow = hsrc + arow;
                frag h0[8], h1[8], h2[8], h3[8];
                load8_issue(hrow,       h0);
                load8_issue(hrow + 256, h1);
                load8_issue(hrow + 512, h2);
                load8_issue(hrow + 768, h3);
                WAIT8(24, h0); ZCON(0, h0);
                WAIT8(16, h1); ZCON(1, h1);
                WAIT8(8,  h2); ZCON(2, h2);
                WAIT8(0,  h3); ZCON(3, h3);
            }
#pragma unroll
            for (int r = 0; r < 4; ++r) {
                float zp = b2f(gzv[r]) + acc0[r];        // bias folded into gx
                float rp = b2f(grv[r]) + acc1[r];
                float z  = 1.f / (1.f + __expf(-zp));
                float rg = 1.f / (1.f + __expf(-rp));
                zg[r] = z;
                store4(rhdst, r, (uint32_t)f2b(rg * hp[r]));
            }
        }

        // ---- arrive: rh fully written by this block (epoch 2t+1) ----
        if constexpr (ROT) arrive_epoch(2u * (unsigned)step + 1u);
        else               bar_arrive();

        if constexpr (ROT) wait_epoch(2u * (unsigned)step + 1u);
        else               bar_wait(++phase);

        // ---- phase A: rh @ w_h_a (acc2), gate + h update ----
        {
            f32x4 acc2 = {};
            if constexpr (ROT) {
                const uint16_t* rrow = rhsrc + arow;
#pragma unroll
                for (int kb = 0; kb < 4; ++kb) {
                    frag rf[8];
#pragma unroll
                    for (int j = 0; j < 8; ++j)
                        rf[j] = *(const frag*)(rrow + kb * 256 + j * 32);
                    ACON(kb, rf);
                }
            } else {
                asm volatile("s_waitcnt vmcnt(0)" ::: "memory");
                const uint16_t* rrow = rhsrc + arow;
                frag r0[8], r1[8], r2[8], r3[8];
                load8_issue(rrow,       r0);
                load8_issue(rrow + 256, r1);
                load8_issue(rrow + 512, r2);
                load8_issue(rrow + 768, r3);
                WAIT8(24, r0); ACON(0, r0);
                WAIT8(16, r1); ACON(1, r1);
                WAIT8(8,  r2); ACON(2, r2);
                WAIT8(0,  r3); ACON(3, r3);
            }
#pragma unroll
            for (int r = 0; r < 4; ++r) {
                float a  = tanhf(b2f(gav[r]) + acc2[r]);
                float hn = (1.f - zg[r]) * hp[r] + zg[r] * a;
                osum[r] += hn;
                hp[r] = hn;
                store4(hdst, r, (uint32_t)f2b(hn));
            }
        }
    }
#pragma unroll
    for (int r = 0; r < 4; ++r)
        out[(int64_t)(brow + r) * HH + jcol] = osum[r];
}

// ---------------- launch ----------------

extern "C" void kernel_launch(void* const* d_in, const int* in_sizes, int n_in,
                              void* d_out, int out_size, void* d_ws, size_t ws_size,
                              hipStream_t stream) {
    const int*   x     = (const int*)d_in[0];
    const float* embed = (const float*)d_in[1];
    const float* w_i   = (const float*)d_in[2];
    const float* w_h   = (const float*)d_in[3];
    const float* bias  = (const float*)d_in[4];
    float* out = (float*)d_out;

    char* ws = (char*)d_ws;
    uint16_t* gx    = (uint16_t*)(ws);                 // 16384*3072*2 = 100663296
    uint16_t* wit   = (uint16_t*)(ws + 100663296);     // 3072*512*2  =   3145728
    uint16_t* wht   = (uint16_t*)(ws + 103809024);     // 3072*1024*2 =   6291456
    uint16_t* words = (uint16_t*)(ws + 110100480);     // 16384*512*2 =  16777216
    uint16_t* hbuf  = (uint16_t*)(ws + 126877696);     // 256*1024*2  =    524288
    uint16_t* rhbuf = (uint16_t*)(ws + 127401984);     // 256*1024*2  =    524288
    unsigned int* flags = (unsigned int*)(ws + 127926272); // 4*1024*4 = 16384
    // rotation region (R14): 65 h slots + 64 rh slots of 512KB, then the
    // R16 strided epoch flags: 4 groups x 64 slots x 256B = 64KB
    const size_t ROT_BASE = 127942656;                 // 16KB-aligned
    uint16_t* hrot  = (uint16_t*)(ws + ROT_BASE);                    // 65*524288
    uint16_t* rhrot = (uint16_t*)(ws + ROT_BASE + 65ull * 524288);   // 64*524288
    unsigned int* flags2 = (unsigned int*)(ws + ROT_BASE + 129ull * 524288);
    const size_t ROT_NEED = ROT_BASE + 129ull * 524288 + 65536;      // 195641344
    const bool rot = ws_size >= ROT_NEED;

    k_gather<<<4096, 256, 0, stream>>>(x, embed, words);
    k_transpose<<<dim3(96, 16), dim3(32, 8), 0, stream>>>(w_i, wit, DD, N3H);
    k_transpose<<<dim3(96, 32), dim3(32, 8), 0, stream>>>(w_h, wht, HH, N3H);
    // zero static hbuf + rhbuf + flags (contiguous 1048576 + 16384 bytes)
    k_zero<<<261, 256, 0, stream>>>((uint4*)(ws + 126877696), (1048576 + 16384) / 16);
    if (rot) { // zero h rotation slot 0 + epoch flags
        k_zero<<<128, 256, 0, stream>>>((uint4*)hrot, 524288 / 16);
        k_zero<<<16, 256, 0, stream>>>((uint4*)flags2, 65536 / 16);
    }
    k_gemm_gx<<<dim3(24, 128), 256, 0, stream>>>(words, wit, bias, gx);
    if (rot)
        k_recur<true><<<dim3(4, 64), 256, 48 * (HH + 8) * 2, stream>>>(
            gx, wht, hrot, rhrot, flags, flags2, out);
    else
        k_recur<false><<<dim3(4, 64), 256, 48 * (HH + 8) * 2, stream>>>(
            gx, wht, hbuf, rhbuf, flags, flags2, out);
}